// Round 1
// baseline (47.259 us; speedup 1.0000x reference)
//
#include <hip/hip_runtime.h>
#include <hip/hip_bf16.h>
#include <math.h>

// Problem constants (fixed by reference): N=2000 nodes, B=2000 bills, D=32, K=3.
#define NN  2000
#define NB  2000
#define DD  32
#define BT  25      // bills per block tile (2000/25 = 80 y-blocks)
#define TPB 256

__global__ __launch_bounds__(TPB) void pol2vec_kernel(
    const int*   __restrict__ events,   // [N,B] 0/1
    const float* __restrict__ tarr,     // [B]
    const float* __restrict__ beta,     // [B]
    const float* __restrict__ gamma,    // [N]
    const float* __restrict__ zb,       // [B,D]
    const float* __restrict__ zp,       // [K,N,D]
    float*       __restrict__ out)      // [1]
{
    __shared__ float s_zb[BT][DD];
    __shared__ float s_t[BT];
    __shared__ float s_be[BT];
    __shared__ float s_red[TPB / 64];

    const int tid = threadIdx.x;
    const int n   = blockIdx.x * TPB + tid;
    const int b0  = blockIdx.y * BT;

    // Stage the bill tile: z_b rows + t + beta (coalesced, one-time)
    for (int i = tid; i < BT * DD; i += TPB) {
        s_zb[i / DD][i % DD] = zb[(size_t)b0 * DD + i];
    }
    if (tid < BT) {
        s_t[tid]  = tarr[b0 + tid];
        s_be[tid] = beta[b0 + tid];
    }
    __syncthreads();

    float acc = 0.f;
    if (n < NN) {
        // Pull this politician's K=3 coefficient rows into registers (96 VGPRs).
        float A[DD], Bv[DD], Cv[DD];
        const float* baseA = zp + (size_t)n * DD;
        const float* baseB = zp + (size_t)NN * DD + (size_t)n * DD;
        const float* baseC = zp + (size_t)2 * NN * DD + (size_t)n * DD;
#pragma unroll
        for (int i = 0; i < DD / 4; ++i) {
            float4 a = ((const float4*)baseA)[i];
            float4 b = ((const float4*)baseB)[i];
            float4 c = ((const float4*)baseC)[i];
            A[4 * i + 0] = a.x; A[4 * i + 1] = a.y; A[4 * i + 2] = a.z; A[4 * i + 3] = a.w;
            Bv[4 * i + 0] = b.x; Bv[4 * i + 1] = b.y; Bv[4 * i + 2] = b.z; Bv[4 * i + 3] = b.w;
            Cv[4 * i + 0] = c.x; Cv[4 * i + 1] = c.y; Cv[4 * i + 2] = c.z; Cv[4 * i + 3] = c.w;
        }
        const float g = gamma[n];
        const int* evrow = events + (size_t)n * NB + b0;

        for (int b = 0; b < BT; ++b) {
            const float t  = s_t[b];
            const float c2 = 0.5f * t * t;   // t^2 / 2!
            float d2 = 0.f;
#pragma unroll
            for (int d = 0; d < DD; ++d) {
                float p  = fmaf(c2, Cv[d], fmaf(t, Bv[d], A[d]));  // pos(t)
                float df = p - s_zb[b][d];
                d2 = fmaf(df, df, d2);
            }
            float L = g + s_be[b] - sqrtf(d2);
            float s = (evrow[b] != 0) ? L : -L;
            // -log_sigmoid(s) = max(-s,0) + log1p(exp(-|s|))   (stable)
            acc += fmaxf(-s, 0.f) + log1pf(__expf(-fabsf(s)));
        }
    }

    // Wave64 shuffle reduction, then cross-wave via LDS, one atomic per block.
#pragma unroll
    for (int o = 32; o > 0; o >>= 1) acc += __shfl_down(acc, o, 64);
    const int wave = tid >> 6;
    const int lane = tid & 63;
    if (lane == 0) s_red[wave] = acc;
    __syncthreads();
    if (tid == 0) {
        float s = 0.f;
#pragma unroll
        for (int w = 0; w < TPB / 64; ++w) s += s_red[w];
        atomicAdd(out, s);
    }
}

extern "C" void kernel_launch(void* const* d_in, const int* in_sizes, int n_in,
                              void* d_out, int out_size, void* d_ws, size_t ws_size,
                              hipStream_t stream) {
    const int*   events = (const int*)d_in[0];    // [N,B]
    const float* tarr   = (const float*)d_in[1];  // [B]
    const float* beta   = (const float*)d_in[2];  // [B]
    const float* gamma  = (const float*)d_in[3];  // [N]
    const float* zb     = (const float*)d_in[4];  // [B,D]
    const float* zp     = (const float*)d_in[5];  // [K,N,D]
    float* out = (float*)d_out;

    // d_out is poisoned once (0xAA) and never re-poisoned between replays:
    // zero it ourselves every launch (graph-capture-safe async memset).
    hipMemsetAsync(out, 0, (size_t)out_size * sizeof(float), stream);

    dim3 grid((NN + TPB - 1) / TPB, NB / BT);
    pol2vec_kernel<<<grid, TPB, 0, stream>>>(events, tarr, beta, gamma, zb, zp, out);
}